// Round 12
// baseline (298.518 us; speedup 1.0000x reference)
//
#include <hip/hip_runtime.h>
#include <math.h>

#define D_MODEL 1024
#define NHEAD   16
#define HDIM    64
#define SEQ     2048
#define BATCH   2
#define NROWS   (BATCH*SEQ)   // 4096

typedef unsigned short u16;
typedef __attribute__((ext_vector_type(4))) unsigned short u16x4;
typedef __attribute__((ext_vector_type(8))) short short8;
typedef __attribute__((ext_vector_type(4))) float f32x4;
typedef __attribute__((ext_vector_type(2))) unsigned int u32x2;

// Flash LDS swizzle: 16B chunk c of row r lives at chunk c ^ (r & 7) (8 chunks/row).
#define SWZ(row, c) (((c) ^ ((row) & 7)) * 8)
// GEMM LDS swizzle for [*][32] bf16 tiles (4 chunks/row) — r9-verified.
#define GF(row) ((((row) + ((row) >> 2))) & 3)

// ---- bf16 helpers (RNE) ----
__device__ __forceinline__ u16 f2bf(float x) {
    unsigned int u = __float_as_uint(x);
    u += 0x7fffu + ((u >> 16) & 1u);
    return (u16)(u >> 16);
}
__device__ __forceinline__ float bf2f(u16 h) {
    return __uint_as_float(((unsigned int)h) << 16);
}
// packed f32x2 -> bf16x2 (HW RNE), no builtin on gfx950 -> inline asm
__device__ __forceinline__ unsigned int cvt_pk_bf16(float a, float b) {
    unsigned int r;
    asm("v_cvt_pk_bf16_f32 %0, %1, %2" : "=v"(r) : "v"(a), "v"(b));
    return r;
}
__device__ __forceinline__ void st8(u16* p, short8 v) {
    u16x4 a, b;
    a[0]=(u16)v[0]; a[1]=(u16)v[1]; a[2]=(u16)v[2]; a[3]=(u16)v[3];
    b[0]=(u16)v[4]; b[1]=(u16)v[5]; b[2]=(u16)v[6]; b[3]=(u16)v[7];
    *(u16x4*)p = a; *(u16x4*)(p + 4) = b;
}
// async global->LDS, 16B/lane. LDS dest = wave-uniform base + lane*16 (m104);
// global src is per-lane (pre-swizzled for bank-conflict-free reads, m173).
__device__ __forceinline__ void gld16(const u16* g, u16* l) {
    __builtin_amdgcn_global_load_lds(
        (const __attribute__((address_space(1))) void*)g,
        (__attribute__((address_space(3))) void*)l, 16, 0, 0);
}

// T1 XCD-aware decode (dispatch XCD = linear_bid % 8, 8 XCDs; verified r11:
// flash FETCH 106.6 -> 20.5 MB). Bijective for gridDim.x in {512, 1024}.
__device__ __forceinline__ void xcd_decode(int bid, int& member, int& g) {
    const int xcd = bid & 7;
    const int rest = bid >> 3;
    member = rest & 15;
    g = ((rest >> 4) << 3) | xcd;
}

// ---------------------------------------------------------------- gdiag
__global__ void gdiag_kernel(const float* __restrict__ A,
                             const float* __restrict__ log_lambda,
                             float* __restrict__ gdiag) {
    int id = blockIdx.x * 256 + threadIdx.x;
    if (id >= NHEAD * HDIM) return;
    int h = id >> 6, d = id & 63;
    float s = 0.f;
#pragma unroll
    for (int i = 0; i < 16; ++i) {
        float a = A[(h * 16 + i) * HDIM + d];
        s += a * a;
    }
    gdiag[id] = (s + __expf(log_lambda[h])) * 1.4426950408889634f;
}

// ---------------------------------------------------------------- prep: fp32 -> bf16 hi/lo
__global__ void prep_split(const float* __restrict__ x,
                           const float* __restrict__ Wq, const float* __restrict__ Wk,
                           const float* __restrict__ Wv, const float* __restrict__ Wo,
                           u16* __restrict__ xh, u16* __restrict__ xl,
                           u16* __restrict__ wqh, u16* __restrict__ wql,
                           u16* __restrict__ wkh, u16* __restrict__ wkl,
                           u16* __restrict__ wvh, u16* __restrict__ woh) {
    int seg = blockIdx.y;
    int i = blockIdx.x * 256 + threadIdx.x;   // float4 index
    const float* src; u16* dh; u16* dl; int n4;
    if      (seg == 0) { src = x;  dh = xh;  dl = xl;      n4 = NROWS * D_MODEL / 4; }
    else if (seg == 1) { src = Wq; dh = wqh; dl = wql;     n4 = D_MODEL * D_MODEL / 4; }
    else if (seg == 2) { src = Wk; dh = wkh; dl = wkl;     n4 = D_MODEL * D_MODEL / 4; }
    else if (seg == 3) { src = Wv; dh = wvh; dl = nullptr; n4 = D_MODEL * D_MODEL / 4; }
    else               { src = Wo; dh = woh; dl = nullptr; n4 = D_MODEL * D_MODEL / 4; }
    if (i >= n4) return;
    float4 v = *(const float4*)&src[(size_t)i * 4];
    float vv[4] = {v.x, v.y, v.z, v.w};
    u16x4 hv, lv;
#pragma unroll
    for (int j = 0; j < 4; ++j) {
        u16 hb = f2bf(vv[j]);
        hv[j] = hb;
        lv[j] = f2bf(vv[j] - bf2f(hb));
    }
    *(u16x4*)&dh[(size_t)i * 4] = hv;
    if (dl) *(u16x4*)&dl[(size_t)i * 4] = lv;
}

// ---------------------------------------------------------------- MFMA NT GEMM (r10 geometry + T1 swizzle)
// out[r][c] = sum_k A[r][k]*W[c][k] + bias[c]; A,W in bf16 hi(/lo), fp32 acc.
// Tile 128x64, BK=32, 512 threads (8 waves), wave = 16 rows x 64 cols -> acc 16 AGPR.
template<int NP3>
__global__ __launch_bounds__(512, 4)
void gemm_mfma(const u16* __restrict__ Ah, const u16* __restrict__ Al,
               const u16* __restrict__ BhA, const u16* __restrict__ BlA, const float* __restrict__ biasA,
               float* outfA, u16* auxhA, u16* auxlA, float* ksumA,
               const u16* __restrict__ BhB, const u16* __restrict__ BlB, const float* __restrict__ biasB,
               float* outfB, u16* auxhB, u16* auxlB, float* ksumB,
               int out_layout) {
    int xtile, g;
    xcd_decode(blockIdx.x, xtile, g);
    const int ytile = g & 31;
    const int z = g >> 5;

    const u16* Bh = (z == 0) ? BhA : BhB;
    const u16* Bl = (z == 0) ? BlA : BlB;
    const float* bias = (z == 0) ? biasA : biasB;
    float* outf = (z == 0) ? outfA : outfB;
    u16* auxh   = (z == 0) ? auxhA : auxhB;
    u16* auxl   = (z == 0) ? auxlA : auxlB;
    float* ksump= (z == 0) ? ksumA : ksumB;

    __shared__ __align__(16) u16 As_h[128][32], Bs_h[64][32];
    __shared__ __align__(16) u16 As_l[NP3 ? 128 : 1][32], Bs_l[NP3 ? 64 : 1][32];

    const int tid = threadIdx.x;
    const int w = tid >> 6, lane = tid & 63, quad = lane >> 4, n16 = lane & 15;
    const int rBase = ytile * 128;
    const int cBase = xtile * 64;

    const int lrow = lane >> 2;          // 0..15
    const int lch  = lane & 3;
    const int arow = w * 16 + lrow;      // A rows for this wave
    const int asc  = ((lch ^ GF(arow)) * 8);
    const int brow = (w & 3) * 16 + lrow;  // B rows (waves 0-3: B_h; waves 4-7: B_l)
    const int bsc  = ((lch ^ GF(brow)) * 8);

    f32x4 acc[4] = {};

    for (int kt = 0; kt < D_MODEL; kt += 32) {
        gld16(&Ah[(size_t)(rBase + arow) * D_MODEL + kt + asc], &As_h[w * 16][0]);
        if (NP3) gld16(&Al[(size_t)(rBase + arow) * D_MODEL + kt + asc], &As_l[w * 16][0]);
        if (w < 4) {
            gld16(&Bh[(size_t)(cBase + brow) * D_MODEL + kt + bsc], &Bs_h[(w & 3) * 16][0]);
        } else if (NP3) {
            gld16(&Bl[(size_t)(cBase + brow) * D_MODEL + kt + bsc], &Bs_l[NP3 ? (w & 3) * 16 : 0][0]);
        }
        __syncthreads();   // compiler drains vmcnt before barrier -> LDS ready

        short8 a_h, a_l;
        {
            const int row = w * 16 + n16;
            const int cc = (quad ^ GF(row)) * 8;
            a_h = *(const short8*)&As_h[row][cc];
            if (NP3) a_l = *(const short8*)&As_l[NP3 ? row : 0][cc];
        }
#pragma unroll
        for (int nt = 0; nt < 4; ++nt) {
            const int row = nt * 16 + n16;
            const int cc = (quad ^ GF(row)) * 8;
            short8 b_h = *(const short8*)&Bs_h[row][cc];
            short8 b_l;
            if (NP3) b_l = *(const short8*)&Bs_l[NP3 ? row : 0][cc];
            acc[nt] = __builtin_amdgcn_mfma_f32_16x16x32_bf16(a_h, b_h, acc[nt], 0, 0, 0);
            if (NP3) {
                acc[nt] = __builtin_amdgcn_mfma_f32_16x16x32_bf16(a_h, b_l, acc[nt], 0, 0, 0);
                acc[nt] = __builtin_amdgcn_mfma_f32_16x16x32_bf16(a_l, b_h, acc[nt], 0, 0, 0);
            }
        }
        __syncthreads();
    }

    // epilogue: C row = quad*4+reg (within 16x16 tile), col = n16
    float csum[4];
#pragma unroll
    for (int nt = 0; nt < 4; ++nt) csum[nt] = 0.f;
#pragma unroll
    for (int nt = 0; nt < 4; ++nt) {
        int c = cBase + nt * 16 + n16;
        float bc = bias[c];
        int rb = rBase + w * 16 + quad * 4;
#pragma unroll
        for (int reg = 0; reg < 4; ++reg) {
            float val = acc[nt][reg] + bc;
            int rr = rb + reg;
            size_t idx = out_layout
                ? ((size_t)(((rr >> 11) * NHEAD + (c >> 6)) * SEQ + (rr & (SEQ - 1)))) * HDIM + (c & 63)
                : (size_t)rr * D_MODEL + c;
            if (outf) outf[idx] = val;
            if (auxh) {
                u16 hb = f2bf(val);
                auxh[idx] = hb;
                if (auxl) auxl[idx] = f2bf(val - bf2f(hb));
            }
            csum[nt] += val;
        }
    }
    if (ksump) {
#pragma unroll
        for (int nt = 0; nt < 4; ++nt) {
            float cs = csum[nt];
            cs += __shfl_xor(cs, 16);
            cs += __shfl_xor(cs, 32);
            if (quad == 0) {
                int c = cBase + nt * 16 + n16;
                int bb = rBase >> 11;
                atomicAdd(&ksump[(bb * NHEAD + (c >> 6)) * HDIM + (c & 63)], cs);
            }
        }
    }
}

// ---------------------------------------------------------------- v transpose: (b,h,t,hd) bf16 -> (b,h,hd,t) bf16
__global__ __launch_bounds__(256)
void vtrans_kernel(const u16* __restrict__ vh, u16* __restrict__ vT) {
    __shared__ u16 tile[64][72];
    const int tid = threadIdx.x;
    const int t0 = blockIdx.x * 64;
    const int bh = blockIdx.y;
    const u16* vp = vh + (size_t)bh * SEQ * HDIM;
#pragma unroll
    for (int s = 0; s < 2; ++s) {
        int id = s * 256 + tid;
        int row = id >> 3, c8 = (id & 7) * 8;
        st8(&tile[row][c8], *(const short8*)&vp[(size_t)(t0 + row) * HDIM + c8]);
    }
    __syncthreads();
#pragma unroll
    for (int s = 0; s < 2; ++s) {
        int id = s * 256 + tid;
        int d = id >> 3, t8 = (id & 7) * 8;
        short8 r;
#pragma unroll
        for (int i = 0; i < 8; ++i) r[i] = (short)tile[t8 + i][d];
        *(short8*)&vT[((size_t)bh * HDIM + d) * SEQ + t0 + t8] = r;
    }
}

// ---------------------------------------------------------------- flash helpers (T15 pipeline pieces)
// QK^T for one 64-key tile: swapped operands, 3-pass split bf16. lg zero-init inside.
__device__ __forceinline__ void qk_mfma(f32x4 (&lg)[2][4],
                                        const u16 (*kh)[64], const u16 (*kl)[64],
                                        const short8 (&sgh)[2][2], const short8 (&sgl)[2][2],
                                        int quad, int n16) {
#pragma unroll
    for (int mt = 0; mt < 2; ++mt)
#pragma unroll
        for (int nt = 0; nt < 4; ++nt) lg[mt][nt] = (f32x4){0.f, 0.f, 0.f, 0.f};
#pragma unroll
    for (int kc = 0; kc < 2; ++kc) {
#pragma unroll
        for (int nt = 0; nt < 4; ++nt) {
            const int row = nt * 16 + n16;
            const int cc = SWZ(row, kc * 4 + quad);
            short8 b_h = *(const short8*)&kh[row][cc];
            short8 b_l = *(const short8*)&kl[row][cc];
#pragma unroll
            for (int mt = 0; mt < 2; ++mt) {
                lg[mt][nt] = __builtin_amdgcn_mfma_f32_16x16x32_bf16(b_h, sgh[mt][kc], lg[mt][nt], 0, 0, 0);
                lg[mt][nt] = __builtin_amdgcn_mfma_f32_16x16x32_bf16(b_l, sgh[mt][kc], lg[mt][nt], 0, 0, 0);
                lg[mt][nt] = __builtin_amdgcn_mfma_f32_16x16x32_bf16(b_h, sgl[mt][kc], lg[mt][nt], 0, 0, 0);
            }
        }
    }
}

// softmax (log2 domain, T13 defer-max, lane-local l) + PV for one tile's logits.
__device__ __forceinline__ void softmax_pv(f32x4 (&lg)[2][4], float (&m_n)[2], float (&l_n)[2],
                                           f32x4 (&oaccv)[2][4],
                                           u16 (*psw)[64],          // ps[w]
                                           const u16 (*vt)[64],     // vTs[buf]
                                           int quad, int n16) {
    float mx[2];
#pragma unroll
    for (int mt = 0; mt < 2; ++mt) {
        float m0 = fmaxf(fmaxf(lg[mt][0][0], lg[mt][0][1]), lg[mt][0][2]);
        m0 = fmaxf(fmaxf(m0, lg[mt][0][3]), lg[mt][1][0]);
        m0 = fmaxf(fmaxf(m0, lg[mt][1][1]), lg[mt][1][2]);
        m0 = fmaxf(fmaxf(m0, lg[mt][1][3]), lg[mt][2][0]);
        m0 = fmaxf(fmaxf(m0, lg[mt][2][1]), lg[mt][2][2]);
        m0 = fmaxf(fmaxf(m0, lg[mt][2][3]), lg[mt][3][0]);
        m0 = fmaxf(fmaxf(m0, lg[mt][3][1]), lg[mt][3][2]);
        m0 = fmaxf(m0, lg[mt][3][3]);
        m0 = fmaxf(m0, __shfl_xor(m0, 16));
        mx[mt] = fmaxf(m0, __shfl_xor(m0, 32));
    }
    const float need = fmaxf(mx[0] - m_n[0], mx[1] - m_n[1]);
    if (!__all(need <= 8.f)) {
#pragma unroll
        for (int mt = 0; mt < 2; ++mt) {
            const float mn = fmaxf(m_n[mt], mx[mt]);
            const float alpha = exp2f(m_n[mt] - mn);
            m_n[mt] = mn;
            l_n[mt] *= alpha;
            const float a0 = __shfl(alpha, quad * 4 + 0);
            const float a1 = __shfl(alpha, quad * 4 + 1);
            const float a2 = __shfl(alpha, quad * 4 + 2);
            const float a3 = __shfl(alpha, quad * 4 + 3);
#pragma unroll
            for (int nt = 0; nt < 4; ++nt) {
                oaccv[mt][nt][0] *= a0; oaccv[mt][nt][1] *= a1;
                oaccv[mt][nt][2] *= a2; oaccv[mt][nt][3] *= a3;
            }
        }
    }
#pragma unroll
    for (int mt = 0; mt < 2; ++mt) {
        const int prow = mt * 16 + n16;
        const float mn = m_n[mt];
        float psum = 0.f;
#pragma unroll
        for (int nt = 0; nt < 4; ++nt) {
#pragma unroll
            for (int r = 0; r < 4; ++r) lg[mt][nt][r] = exp2f(lg[mt][nt][r] - mn);
            u32x2 pk;
            pk[0] = cvt_pk_bf16(lg[mt][nt][0], lg[mt][nt][1]);
            pk[1] = cvt_pk_bf16(lg[mt][nt][2], lg[mt][nt][3]);
            *(u32x2*)&psw[prow][SWZ(prow, nt * 2 + (quad >> 1)) + (quad & 1) * 4] = pk;
            psum += (lg[mt][nt][0] + lg[mt][nt][1]) + (lg[mt][nt][2] + lg[mt][nt][3]);
        }
        l_n[mt] += psum;
    }
    // PV: same-wave ds write->read (DS pipe in-order)
    short8 pa[2][2];
#pragma unroll
    for (int mt = 0; mt < 2; ++mt) {
        const int prow = mt * 16 + n16;
        pa[mt][0] = *(const short8*)&psw[prow][SWZ(prow, quad)];
        pa[mt][1] = *(const short8*)&psw[prow][SWZ(prow, quad + 4)];
    }
#pragma unroll
    for (int nt = 0; nt < 4; ++nt) {
        const int row = nt * 16 + n16;
        short8 v0 = *(const short8*)&vt[row][SWZ(row, quad)];
        short8 v1 = *(const short8*)&vt[row][SWZ(row, quad + 4)];
#pragma unroll
        for (int mt = 0; mt < 2; ++mt) {
            oaccv[mt][nt] = __builtin_amdgcn_mfma_f32_16x16x32_bf16(pa[mt][0], v0, oaccv[mt][nt], 0, 0, 0);
            oaccv[mt][nt] = __builtin_amdgcn_mfma_f32_16x16x32_bf16(pa[mt][1], v1, oaccv[mt][nt], 0, 0, 0);
        }
    }
}

// ---------------------------------------------------------------- flash attention (T15 double-pipeline)
// QBLK=128: 4 waves x 32 queries (2 fragments mt). Swapped-operand QK^T; T13 defer-max;
// lane-local l; XOR chunk swizzle; T1 XCD-grid (r11: FETCH 106->20.5 MB).
// PIPELINE: body j = { QK[j] (MFMA pipe, lgC) || softmax+PV[j-1] (VALU/DS pipes, lgP) } --
// independent streams the compiler can interleave. K double-buffered; V TRIPLE-buffered
// (PV[j-1] reads V[j-1] while stage fills V[j+1]). LDS 64KB -> 2 blocks/CU (unchanged).
__global__ __launch_bounds__(256, 2)
void flash_mfma(const float* __restrict__ q, const u16* __restrict__ kh,
                const u16* __restrict__ kl, const u16* __restrict__ vT,
                const float* __restrict__ ksum, const float* __restrict__ gdiag,
                u16* __restrict__ o) {
    __shared__ __align__(16) u16 khs[2][64][64], kls[2][64][64], vTs[3][64][64];
    __shared__ __align__(16) u16 ps[4][32][64];

    const int tid = threadIdx.x;
    const int w = tid >> 6, lane = tid & 63, quad = lane >> 4, n16 = lane & 15;
    int qblk, g;
    xcd_decode(blockIdx.x, qblk, g);
    const int t0 = qblk * 128;
    const int h = g & 15, b = g >> 4;
    const size_t bh = (size_t)b * NHEAD + h;
    const float* qp = q + bh * SEQ * HDIM;
    const u16* khp = kh + bh * SEQ * HDIM;
    const u16* klp = kl + bh * SEQ * HDIM;
    const u16* vtp = vT + bh * HDIM * SEQ;

    // Sg fragments: sg*[mt][kc][j], d = kc*32 + quad*8 + j, query = t0+w*32+mt*16+n16
    short8 sgh[2][2], sgl[2][2];
#pragma unroll
    for (int mt = 0; mt < 2; ++mt) {
        int qrow = t0 + w * 32 + mt * 16 + n16;
#pragma unroll
        for (int kc = 0; kc < 2; ++kc) {
            int d0 = kc * 32 + quad * 8;
            float4 q0 = *(const float4*)&qp[(size_t)qrow * HDIM + d0];
            float4 q1 = *(const float4*)&qp[(size_t)qrow * HDIM + d0 + 4];
            float4 k0 = *(const float4*)&ksum[bh * HDIM + d0];
            float4 k1 = *(const float4*)&ksum[bh * HDIM + d0 + 4];
            float4 g0 = *(const float4*)&gdiag[(size_t)h * HDIM + d0];
            float4 g1 = *(const float4*)&gdiag[(size_t)h * HDIM + d0 + 4];
            float sg[8];
            sg[0] = (2048.f * q0.x - k0.x) * g0.x; sg[1] = (2048.f * q0.y - k0.y) * g0.y;
            sg[2] = (2048.f * q0.z - k0.z) * g0.z; sg[3] = (2048.f * q0.w - k0.w) * g0.w;
            sg[4] = (2048.f * q1.x - k1.x) * g1.x; sg[5] = (2048.f * q1.y - k1.y) * g1.y;
            sg[6] = (2048.f * q1.z - k1.z) * g1.z; sg[7] = (2048.f * q1.w - k1.w) * g1.w;
#pragma unroll
            for (int j = 0; j < 8; ++j) {
                u16 hb = f2bf(sg[j]);
                sgh[mt][kc][j] = (short)hb;
                sgl[mt][kc][j] = (short)f2bf(sg[j] - bf2f(hb));
            }
        }
    }

    f32x4 oaccv[2][4] = {};
    f32x4 lgP[2][4];
    float m_n[2] = {-INFINITY, -INFINITY};
    float l_n[2] = {0.f, 0.f};     // lane-local partial sums; reduced in epilogue

    const int srow = tid >> 3;            // 0..31
    const int sc   = tid & 7;             // chunk
    const int scg  = sc * 8;              // global u16 col
    const int scl  = SWZ(srow, sc);       // LDS u16 col

    const int NT = SEQ / 64;              // 32 tiles

    // prologue: stage tile 0 into K-buf 0 / V-buf 0
    *(short8*)&khs[0][srow][scl]      = *(const short8*)&khp[(size_t)srow * HDIM + scg];
    *(short8*)&khs[0][srow + 32][scl] = *(const short8*)&khp[(size_t)(srow + 32) * HDIM + scg];
    *(short8*)&kls[0][srow][scl]      = *(const short8*)&klp[(size_t)srow * HDIM + scg];
    *(short8*)&kls[0][srow + 32][scl] = *(const short8*)&klp[(size_t)(srow + 32) * HDIM + scg];
    *(short8*)&vTs[0][srow][scl]      = *(const short8*)&vtp[(size_t)srow * SEQ + scg];
    *(short8*)&vTs[0][srow + 32][scl] = *(const short8*)&vtp[(size_t)(srow + 32) * SEQ + scg];
    __syncthreads();

    // QK of tile 0 -> lgP, then stage tile 1 into K-buf 1 / V-buf 1 (untouched buffers)
    qk_mfma(lgP, khs[0], kls[0], sgh, sgl, quad, n16);
    {
        const int j0 = 64;
        *(short8*)&khs[1][srow][scl]      = *(const short8*)&khp[(size_t)(j0 + srow) * HDIM + scg];
        *(short8*)&khs[1][srow + 32][scl] = *(const short8*)&khp[(size_t)(j0 + srow + 32) * HDIM + scg];
        *(short8*)&kls[1][srow][scl]      = *(const short8*)&klp[(size_t)(j0 + srow) * HDIM + scg];
        *(short8*)&kls[1][srow + 32][scl] = *(const short8*)&klp[(size_t)(j0 + srow + 32) * HDIM + scg];
        *(short8*)&vTs[1][srow][scl]      = *(const short8*)&vtp[(size_t)srow * SEQ + j0 + scg];
        *(short8*)&vTs[1][srow + 32][scl] = *(const short8*)&vtp[(size_t)(srow + 32) * SEQ + j0 + scg];
    }

    for (int j = 1; j < NT; ++j) {
        __syncthreads();   // tile j staged for all waves; all waves past QK[j-1] & PV[j-2]
        const int kcur = j & 1;
        const int vprev = (j - 1) % 3;
        const bool pf = (j + 1 < NT);

        // T14 issue-early: next tile's global loads
        short8 rk0h, rk1h, rk0l, rk1l, rv0, rv1;
        if (pf) {
            const int jn = (j + 1) * 64;
            rk0h = *(const short8*)&khp[(size_t)(jn + srow) * HDIM + scg];
            rk1h = *(const short8*)&khp[(size_t)(jn + srow + 32) * HDIM + scg];
            rk0l = *(const short8*)&klp[(size_t)(jn + srow) * HDIM + scg];
            rk1l = *(const short8*)&klp[(size_t)(jn + srow + 32) * HDIM + scg];
            rv0  = *(const short8*)&vtp[(size_t)srow * SEQ + jn + scg];
            rv1  = *(const short8*)&vtp[(size_t)(srow + 32) * SEQ + jn + scg];
        }

        // MFMA stream: QK[j] -> lgC ; VALU/DS stream: softmax+PV[j-1] from lgP.
        f32x4 lgC[2][4];
        qk_mfma(lgC, khs[kcur], kls[kcur], sgh, sgl, quad, n16);
        softmax_pv(lgP, m_n, l_n, oaccv, ps[w], vTs[vprev], quad, n16);

        // stage-write tile j+1 (K into buf (j+1)&1 — its last readers finished before
        // this iteration's top barrier; V into buf (j+1)%3 — last read 2 tiles ago)
        if (pf) {
            const int kn = (j + 1) & 1;
            const int vn = (j + 1) % 3;
            *(short8*)&khs[kn][srow][scl] = rk0h;  *(short8*)&khs[kn][srow + 32][scl] = rk1h;
            *(short8*)&kls[kn][srow][scl] = rk0l;  *(short8*)&kls[kn][srow + 32][scl] = rk1l;
            *(short8*)&vTs[vn][srow][scl] = rv0;   *(short8*)&vTs[vn][srow + 32][scl] = rv1;
        }

        // rotate logits
#pragma unroll
        for (int mt = 0; mt < 2; ++mt)
#pragma unroll
            for (int nt = 0; nt < 4; ++nt) lgP[mt][nt] = lgC[mt][nt];
    }

    // drain: softmax+PV of last tile (V staged before the final top barrier)
    softmax_pv(lgP, m_n, l_n, oaccv, ps[w], vTs[(NT - 1) % 3], quad, n16);

    // epilogue: reduce lane-local l, write o_hi bf16, row-major (b, t, h*64+d)
#pragma unroll
    for (int mt = 0; mt < 2; ++mt) {
        float l = l_n[mt];
        l += __shfl_xor(l, 16);
        l += __shfl_xor(l, 32);
        l_n[mt] = l;
    }
#pragma unroll
    for (int mt = 0; mt < 2; ++mt) {
#pragma unroll
        for (int r = 0; r < 4; ++r) {
            float lr = __shfl(l_n[mt], quad * 4 + r);
            float inv = 1.f / lr;
            int t = t0 + w * 32 + mt * 16 + quad * 4 + r;
#pragma unroll
            for (int nt = 0; nt < 4; ++nt) {
                int d = nt * 16 + n16;
                o[((size_t)(b * SEQ + t)) * D_MODEL + h * HDIM + d] = f2bf(oaccv[mt][nt][r] * inv);
            }
        }
    }
}

// ---------------------------------------------------------------- launcher
extern "C" void kernel_launch(void* const* d_in, const int* in_sizes, int n_in,
                              void* d_out, int out_size, void* d_ws, size_t ws_size,
                              hipStream_t stream) {
    const float* x  = (const float*)d_in[0];
    const float* Wq = (const float*)d_in[1];
    const float* bq = (const float*)d_in[2];
    const float* Wk = (const float*)d_in[3];
    const float* bk = (const float*)d_in[4];
    const float* Wv = (const float*)d_in[5];
    const float* bv = (const float*)d_in[6];
    const float* Wo = (const float*)d_in[7];
    const float* bo = (const float*)d_in[8];
    const float* A  = (const float*)d_in[9];
    const float* ll = (const float*)d_in[10];
    float* out = (float*)d_out;

    const size_t NQKV = (size_t)NROWS * D_MODEL;   // 4,194,304
    const size_t NW = (size_t)D_MODEL * D_MODEL;   // 1,048,576
    char* base = (char*)d_ws;
    float* q_ws = (float*)base;            base += NQKV * 4;
    u16* xh  = (u16*)base;                 base += NQKV * 2;   // reused as o_hi after QKV
    u16* xl  = (u16*)base;                 base += NQKV * 2;   // reused as vT after QKV
    u16* khw = (u16*)base;                 base += NQKV * 2;
    u16* klw = (u16*)base;                 base += NQKV * 2;
    u16* vhw = (u16*)base;                 base += NQKV * 2;
    u16* wqh = (u16*)base;                 base += NW * 2;
    u16* wql = (u16*)base;                 base += NW * 2;
    u16* wkh = (u16*)base;                 base += NW * 2;
    u16* wkl = (u16*)base;                 base += NW * 2;
    u16* wvh = (u16*)base;                 base += NW * 2;
    u16* woh = (u16*)base;                 base += NW * 2;
    float* gd_ws   = (float*)base;         base += NHEAD * HDIM * 4;
    float* ksum_ws = (float*)base;         base += BATCH * NHEAD * HDIM * 4;

    hipMemsetAsync(ksum_ws, 0, BATCH * NHEAD * HDIM * sizeof(float), stream);

    prep_split<<<dim3(4096, 5), 256, 0, stream>>>(x, Wq, Wk, Wv, Wo,
                                                  xh, xl, wqh, wql, wkh, wkl, wvh, woh);
    gdiag_kernel<<<4, 256, 0, stream>>>(A, ll, gd_ws);

    // Q (g<32) + K (g>=32): 3-pass split-bf16; K writes k_hi/k_lo + ksum atomics
    gemm_mfma<1><<<1024, 512, 0, stream>>>(
        xh, xl,
        wqh, wql, bq, q_ws, nullptr, nullptr, nullptr,
        wkh, wkl, bk, nullptr, khw, klw, ksum_ws,
        1);
    // V: 1-pass bf16, writes v_hi bf16 only
    gemm_mfma<0><<<512, 512, 0, stream>>>(
        xh, nullptr,
        wvh, nullptr, bv, nullptr, vhw, nullptr, nullptr,
        wvh, nullptr, bv, nullptr, vhw, nullptr, nullptr,
        1);

    u16* vTw = xl;   // alias: x_lo dead after QKV GEMMs
    u16* ohw = xh;   // alias: x_hi dead after QKV GEMMs
    vtrans_kernel<<<dim3(SEQ / 64, BATCH * NHEAD), 256, 0, stream>>>(vhw, vTw);

    flash_mfma<<<512, 256, 0, stream>>>(
        q_ws, khw, klw, vTw, ksum_ws, gd_ws, ohw);

    // out-proj: 1-pass bf16, row-major fp32 output
    gemm_mfma<0><<<512, 512, 0, stream>>>(
        ohw, nullptr,
        woh, nullptr, bo, out, nullptr, nullptr, nullptr,
        woh, nullptr, bo, out, nullptr, nullptr, nullptr,
        0);
}

// Round 13
// 288.512 us; speedup vs baseline: 1.0347x; 1.0347x over previous
//
#include <hip/hip_runtime.h>
#include <math.h>

#define D_MODEL 1024
#define NHEAD   16
#define HDIM    64
#define SEQ     2048
#define BATCH   2
#define NROWS   (BATCH*SEQ)   // 4096

typedef unsigned short u16;
typedef __attribute__((ext_vector_type(4))) unsigned short u16x4;
typedef __attribute__((ext_vector_type(8))) short short8;
typedef __attribute__((ext_vector_type(4))) float f32x4;
typedef __attribute__((ext_vector_type(2))) unsigned int u32x2;

// Flash LDS swizzle: 16B chunk c of row r lives at chunk c ^ (r & 7) (8 chunks/row).
#define SWZ(row, c) (((c) ^ ((row) & 7)) * 8)
// GEMM LDS swizzle for [*][32] bf16 tiles (4 chunks/row) — r9-verified.
#define GF(row) ((((row) + ((row) >> 2))) & 3)

// ---- bf16 helpers (RNE) ----
__device__ __forceinline__ u16 f2bf(float x) {
    unsigned int u = __float_as_uint(x);
    u += 0x7fffu + ((u >> 16) & 1u);
    return (u16)(u >> 16);
}
__device__ __forceinline__ float bf2f(u16 h) {
    return __uint_as_float(((unsigned int)h) << 16);
}
// packed f32x2 -> bf16x2 (HW RNE), no builtin on gfx950 -> inline asm
__device__ __forceinline__ unsigned int cvt_pk_bf16(float a, float b) {
    unsigned int r;
    asm("v_cvt_pk_bf16_f32 %0, %1, %2" : "=v"(r) : "v"(a), "v"(b));
    return r;
}
// async global->LDS, 16B/lane. LDS dest = wave-uniform base + lane*16 (m104);
// global src is per-lane (pre-swizzled for bank-conflict-free reads, m173).
__device__ __forceinline__ void gld16(const u16* g, u16* l) {
    __builtin_amdgcn_global_load_lds(
        (const __attribute__((address_space(1))) void*)g,
        (__attribute__((address_space(3))) void*)l, 16, 0, 0);
}

// T1 XCD-aware decode (dispatch XCD = linear_bid % 8, 8 XCDs; verified r11:
// flash FETCH 106.6 -> 20.5 MB). Bijective for any gridDim.x multiple of 128
// (512, 1024, 1536 used here). Members 0..15 of group g co-locate on XCD g&7.
__device__ __forceinline__ void xcd_decode(int bid, int& member, int& g) {
    const int xcd = bid & 7;
    const int rest = bid >> 3;
    member = rest & 15;
    g = ((rest >> 4) << 3) | xcd;
}

// ---------------------------------------------------------------- gdiag
__global__ void gdiag_kernel(const float* __restrict__ A,
                             const float* __restrict__ log_lambda,
                             float* __restrict__ gdiag) {
    int id = blockIdx.x * 256 + threadIdx.x;
    if (id >= NHEAD * HDIM) return;
    int h = id >> 6, d = id & 63;
    float s = 0.f;
#pragma unroll
    for (int i = 0; i < 16; ++i) {
        float a = A[(h * 16 + i) * HDIM + d];
        s += a * a;
    }
    gdiag[id] = (s + __expf(log_lambda[h])) * 1.4426950408889634f;
}

// ---------------------------------------------------------------- prep: fp32 -> bf16 hi/lo
__global__ void prep_split(const float* __restrict__ x,
                           const float* __restrict__ Wq, const float* __restrict__ Wk,
                           const float* __restrict__ Wv, const float* __restrict__ Wo,
                           u16* __restrict__ xh, u16* __restrict__ xl,
                           u16* __restrict__ wqh, u16* __restrict__ wql,
                           u16* __restrict__ wkh, u16* __restrict__ wkl,
                           u16* __restrict__ wvh, u16* __restrict__ woh) {
    int seg = blockIdx.y;
    int i = blockIdx.x * 256 + threadIdx.x;   // float4 index
    const float* src; u16* dh; u16* dl; int n4;
    if      (seg == 0) { src = x;  dh = xh;  dl = xl;      n4 = NROWS * D_MODEL / 4; }
    else if (seg == 1) { src = Wq; dh = wqh; dl = wql;     n4 = D_MODEL * D_MODEL / 4; }
    else if (seg == 2) { src = Wk; dh = wkh; dl = wkl;     n4 = D_MODEL * D_MODEL / 4; }
    else if (seg == 3) { src = Wv; dh = wvh; dl = nullptr; n4 = D_MODEL * D_MODEL / 4; }
    else               { src = Wo; dh = woh; dl = nullptr; n4 = D_MODEL * D_MODEL / 4; }
    if (i >= n4) return;
    float4 v = *(const float4*)&src[(size_t)i * 4];
    float vv[4] = {v.x, v.y, v.z, v.w};
    u16x4 hv, lv;
#pragma unroll
    for (int j = 0; j < 4; ++j) {
        u16 hb = f2bf(vv[j]);
        hv[j] = hb;
        lv[j] = f2bf(vv[j] - bf2f(hb));
    }
    *(u16x4*)&dh[(size_t)i * 4] = hv;
    if (dl) *(u16x4*)&dl[(size_t)i * 4] = lv;
}

// ---------------------------------------------------------------- MFMA NT GEMM (merged QKV / O)
// out[r][c] = sum_k A[r][k]*W[c][k] + bias[c]; A,W in bf16 hi(/lo), fp32 acc.
// Tile 128x64, BK=32, 512 threads (8 waves), wave = 16 rows x 64 cols -> acc 16 AGPR.
// z = g>>5 selects operand set {0,1,2}; np3 = (np3_mask>>z)&1 (3-pass split-bf16);
// layout = (layouts>>(4*z))&15: 0 = row-major fp32, 1 = split-head (b,h,t,d) fp32/bf16,
// 2 = TRANSPOSED bf16 vT (b,h,d,t) — folds the old vtrans kernel into the epilogue
// (4 consecutive-t regs -> one aligned 8B store).
__global__ __launch_bounds__(512, 4)
void gemm_mfma(const u16* __restrict__ Ah, const u16* __restrict__ Al,
               const u16* __restrict__ Bh0, const u16* __restrict__ Bl0, const float* __restrict__ bias0,
               float* outf0, u16* auxh0, u16* auxl0, float* ksum0,
               const u16* __restrict__ Bh1, const u16* __restrict__ Bl1, const float* __restrict__ bias1,
               float* outf1, u16* auxh1, u16* auxl1, float* ksum1,
               const u16* __restrict__ Bh2, const float* __restrict__ bias2, u16* __restrict__ auxh2,
               int np3_mask, int layouts) {
    int xtile, g;
    xcd_decode(blockIdx.x, xtile, g);
    const int ytile = g & 31;
    const int z = g >> 5;

    const u16* Bh = (z == 0) ? Bh0 : (z == 1) ? Bh1 : Bh2;
    const u16* Bl = (z == 0) ? Bl0 : (z == 1) ? Bl1 : nullptr;
    const float* bias = (z == 0) ? bias0 : (z == 1) ? bias1 : bias2;
    float* outf = (z == 0) ? outf0 : (z == 1) ? outf1 : nullptr;
    u16* auxh   = (z == 0) ? auxh0 : (z == 1) ? auxh1 : auxh2;
    u16* auxl   = (z == 0) ? auxl0 : (z == 1) ? auxl1 : nullptr;
    float* ksump= (z == 0) ? ksum0 : (z == 1) ? ksum1 : nullptr;
    const bool np3 = (np3_mask >> z) & 1;
    const int layout = (layouts >> (4 * z)) & 15;

    __shared__ __align__(16) u16 As_h[128][32], Bs_h[64][32];
    __shared__ __align__(16) u16 As_l[128][32], Bs_l[64][32];

    const int tid = threadIdx.x;
    const int w = tid >> 6, lane = tid & 63, quad = lane >> 4, n16 = lane & 15;
    const int rBase = ytile * 128;
    const int cBase = xtile * 64;

    const int lrow = lane >> 2;          // 0..15
    const int lch  = lane & 3;
    const int arow = w * 16 + lrow;      // A rows for this wave
    const int asc  = ((lch ^ GF(arow)) * 8);
    const int brow = (w & 3) * 16 + lrow;  // B rows (waves 0-3: B_h; waves 4-7: B_l)
    const int bsc  = ((lch ^ GF(brow)) * 8);

    f32x4 acc[4] = {};

    for (int kt = 0; kt < D_MODEL; kt += 32) {
        gld16(&Ah[(size_t)(rBase + arow) * D_MODEL + kt + asc], &As_h[w * 16][0]);
        if (np3) gld16(&Al[(size_t)(rBase + arow) * D_MODEL + kt + asc], &As_l[w * 16][0]);
        if (w < 4) {
            gld16(&Bh[(size_t)(cBase + brow) * D_MODEL + kt + bsc], &Bs_h[(w & 3) * 16][0]);
        } else if (np3) {
            gld16(&Bl[(size_t)(cBase + brow) * D_MODEL + kt + bsc], &Bs_l[(w & 3) * 16][0]);
        }
        __syncthreads();   // compiler drains vmcnt before barrier -> LDS ready

        short8 a_h, a_l;
        {
            const int row = w * 16 + n16;
            const int cc = (quad ^ GF(row)) * 8;
            a_h = *(const short8*)&As_h[row][cc];
            if (np3) a_l = *(const short8*)&As_l[row][cc];
        }
#pragma unroll
        for (int nt = 0; nt < 4; ++nt) {
            const int row = nt * 16 + n16;
            const int cc = (quad ^ GF(row)) * 8;
            short8 b_h = *(const short8*)&Bs_h[row][cc];
            acc[nt] = __builtin_amdgcn_mfma_f32_16x16x32_bf16(a_h, b_h, acc[nt], 0, 0, 0);
            if (np3) {
                short8 b_l = *(const short8*)&Bs_l[row][cc];
                acc[nt] = __builtin_amdgcn_mfma_f32_16x16x32_bf16(a_h, b_l, acc[nt], 0, 0, 0);
                acc[nt] = __builtin_amdgcn_mfma_f32_16x16x32_bf16(a_l, b_h, acc[nt], 0, 0, 0);
            }
        }
        __syncthreads();
    }

    // ---- epilogue ----
    if (layout == 2) {
        // transposed bf16 write: vT[(b*16+h)*64 + d][t], 4 consecutive t per thread
#pragma unroll
        for (int nt = 0; nt < 4; ++nt) {
            const int c = cBase + nt * 16 + n16;
            const float bc = bias[c];
            const int rb = rBase + w * 16 + quad * 4;
            const int b = rb >> 11, t = rb & (SEQ - 1);
            u16x4 tv;
#pragma unroll
            for (int reg = 0; reg < 4; ++reg) tv[reg] = f2bf(acc[nt][reg] + bc);
            *(u16x4*)&auxh[(((size_t)b * NHEAD + (c >> 6)) * HDIM + (c & 63)) * SEQ + t] = tv;
        }
        return;
    }

    float csum[4];
#pragma unroll
    for (int nt = 0; nt < 4; ++nt) csum[nt] = 0.f;
#pragma unroll
    for (int nt = 0; nt < 4; ++nt) {
        int c = cBase + nt * 16 + n16;
        float bc = bias[c];
        int rb = rBase + w * 16 + quad * 4;
#pragma unroll
        for (int reg = 0; reg < 4; ++reg) {
            float val = acc[nt][reg] + bc;
            int rr = rb + reg;
            size_t idx = (layout == 1)
                ? ((size_t)(((rr >> 11) * NHEAD + (c >> 6)) * SEQ + (rr & (SEQ - 1)))) * HDIM + (c & 63)
                : (size_t)rr * D_MODEL + c;
            if (outf) outf[idx] = val;
            if (auxh) {
                u16 hb = f2bf(val);
                auxh[idx] = hb;
                if (auxl) auxl[idx] = f2bf(val - bf2f(hb));
            }
            csum[nt] += val;
        }
    }
    if (ksump) {
#pragma unroll
        for (int nt = 0; nt < 4; ++nt) {
            float cs = csum[nt];
            cs += __shfl_xor(cs, 16);
            cs += __shfl_xor(cs, 32);
            if (quad == 0) {
                int c = cBase + nt * 16 + n16;
                int bb = rBase >> 11;
                atomicAdd(&ksump[(bb * NHEAD + (c >> 6)) * HDIM + (c & 63)], cs);
            }
        }
    }
}

// ---------------------------------------------------------------- flash helpers (T15 pipeline pieces)
// QK^T for one 64-key tile: swapped operands, 3-pass split bf16. lg zero-init inside.
__device__ __forceinline__ void qk_mfma(f32x4 (&lg)[2][4],
                                        const u16 (*kh)[64], const u16 (*kl)[64],
                                        const short8 (&sgh)[2][2], const short8 (&sgl)[2][2],
                                        int quad, int n16) {
#pragma unroll
    for (int mt = 0; mt < 2; ++mt)
#pragma unroll
        for (int nt = 0; nt < 4; ++nt) lg[mt][nt] = (f32x4){0.f, 0.f, 0.f, 0.f};
#pragma unroll
    for (int kc = 0; kc < 2; ++kc) {
#pragma unroll
        for (int nt = 0; nt < 4; ++nt) {
            const int row = nt * 16 + n16;
            const int cc = SWZ(row, kc * 4 + quad);
            short8 b_h = *(const short8*)&kh[row][cc];
            short8 b_l = *(const short8*)&kl[row][cc];
#pragma unroll
            for (int mt = 0; mt < 2; ++mt) {
                lg[mt][nt] = __builtin_amdgcn_mfma_f32_16x16x32_bf16(b_h, sgh[mt][kc], lg[mt][nt], 0, 0, 0);
                lg[mt][nt] = __builtin_amdgcn_mfma_f32_16x16x32_bf16(b_l, sgh[mt][kc], lg[mt][nt], 0, 0, 0);
                lg[mt][nt] = __builtin_amdgcn_mfma_f32_16x16x32_bf16(b_h, sgl[mt][kc], lg[mt][nt], 0, 0, 0);
            }
        }
    }
}

// softmax (log2 domain, T13 defer-max, lane-local l) + PV for one tile's logits.
__device__ __forceinline__ void softmax_pv(f32x4 (&lg)[2][4], float (&m_n)[2], float (&l_n)[2],
                                           f32x4 (&oaccv)[2][4],
                                           u16 (*psw)[64],          // ps[w]
                                           const u16 (*vt)[64],     // vTs[buf]
                                           int quad, int n16) {
    float mx[2];
#pragma unroll
    for (int mt = 0; mt < 2; ++mt) {
        float m0 = fmaxf(fmaxf(lg[mt][0][0], lg[mt][0][1]), lg[mt][0][2]);
        m0 = fmaxf(fmaxf(m0, lg[mt][0][3]), lg[mt][1][0]);
        m0 = fmaxf(fmaxf(m0, lg[mt][1][1]), lg[mt][1][2]);
        m0 = fmaxf(fmaxf(m0, lg[mt][1][3]), lg[mt][2][0]);
        m0 = fmaxf(fmaxf(m0, lg[mt][2][1]), lg[mt][2][2]);
        m0 = fmaxf(fmaxf(m0, lg[mt][2][3]), lg[mt][3][0]);
        m0 = fmaxf(fmaxf(m0, lg[mt][3][1]), lg[mt][3][2]);
        m0 = fmaxf(m0, lg[mt][3][3]);
        m0 = fmaxf(m0, __shfl_xor(m0, 16));
        mx[mt] = fmaxf(m0, __shfl_xor(m0, 32));
    }
    const float need = fmaxf(mx[0] - m_n[0], mx[1] - m_n[1]);
    if (!__all(need <= 8.f)) {
#pragma unroll
        for (int mt = 0; mt < 2; ++mt) {
            const float mn = fmaxf(m_n[mt], mx[mt]);
            const float alpha = exp2f(m_n[mt] - mn);
            m_n[mt] = mn;
            l_n[mt] *= alpha;
            const float a0 = __shfl(alpha, quad * 4 + 0);
            const float a1 = __shfl(alpha, quad * 4 + 1);
            const float a2 = __shfl(alpha, quad * 4 + 2);
            const float a3 = __shfl(alpha, quad * 4 + 3);
#pragma unroll
            for (int nt = 0; nt < 4; ++nt) {
                oaccv[mt][nt][0] *= a0; oaccv[mt][nt][1] *= a1;
                oaccv[mt][nt][2] *= a2; oaccv[mt][nt][3] *= a3;
            }
        }
    }
#pragma unroll
    for (int mt = 0; mt < 2; ++mt) {
        const int prow = mt * 16 + n16;
        const float mn = m_n[mt];
        float psum = 0.f;
#pragma unroll
        for (int nt = 0; nt < 4; ++nt) {
#pragma unroll
            for (int r = 0; r < 4; ++r) lg[mt][nt][r] = exp2f(lg[mt][nt][r] - mn);
            u32x2 pk;
            pk[0] = cvt_pk_bf16(lg[mt][nt][0], lg[mt][nt][1]);
            pk[1] = cvt_pk_bf16(lg[mt][nt][2], lg[mt][nt][3]);
            *(u32x2*)&psw[prow][SWZ(prow, nt * 2 + (quad >> 1)) + (quad & 1) * 4] = pk;
            psum += (lg[mt][nt][0] + lg[mt][nt][1]) + (lg[mt][nt][2] + lg[mt][nt][3]);
        }
        l_n[mt] += psum;
    }
    // PV: same-wave ds write->read (DS pipe in-order)
    short8 pa[2][2];
#pragma unroll
    for (int mt = 0; mt < 2; ++mt) {
        const int prow = mt * 16 + n16;
        pa[mt][0] = *(const short8*)&psw[prow][SWZ(prow, quad)];
        pa[mt][1] = *(const short8*)&psw[prow][SWZ(prow, quad + 4)];
    }
#pragma unroll
    for (int nt = 0; nt < 4; ++nt) {
        const int row = nt * 16 + n16;
        short8 v0 = *(const short8*)&vt[row][SWZ(row, quad)];
        short8 v1 = *(const short8*)&vt[row][SWZ(row, quad + 4)];
#pragma unroll
        for (int mt = 0; mt < 2; ++mt) {
            oaccv[mt][nt] = __builtin_amdgcn_mfma_f32_16x16x32_bf16(pa[mt][0], v0, oaccv[mt][nt], 0, 0, 0);
            oaccv[mt][nt] = __builtin_amdgcn_mfma_f32_16x16x32_bf16(pa[mt][1], v1, oaccv[mt][nt], 0, 0, 0);
        }
    }
}

// ---------------------------------------------------------------- flash attention (T15 double-pipeline, r12)
// QBLK=128: 4 waves x 32 queries (2 fragments mt). Swapped-operand QK^T; T13 defer-max;
// lane-local l; XOR chunk swizzle; T1 XCD-grid (r11: FETCH 106->20.5 MB).
// PIPELINE: body j = { QK[j] (MFMA pipe, lgC) || softmax+PV[j-1] (VALU/DS pipes, lgP) }.
// K double-buffered; V TRIPLE-buffered. LDS 72KB -> 2 blocks/CU.
__global__ __launch_bounds__(256, 2)
void flash_mfma(const float* __restrict__ q, const u16* __restrict__ kh,
                const u16* __restrict__ kl, const u16* __restrict__ vT,
                const float* __restrict__ ksum, const float* __restrict__ gdiag,
                u16* __restrict__ o) {
    __shared__ __align__(16) u16 khs[2][64][64], kls[2][64][64], vTs[3][64][64];
    __shared__ __align__(16) u16 ps[4][32][64];

    const int tid = threadIdx.x;
    const int w = tid >> 6, lane = tid & 63, quad = lane >> 4, n16 = lane & 15;
    int qblk, g;
    xcd_decode(blockIdx.x, qblk, g);
    const int t0 = qblk * 128;
    const int h = g & 15, b = g >> 4;
    const size_t bh = (size_t)b * NHEAD + h;
    const float* qp = q + bh * SEQ * HDIM;
    const u16* khp = kh + bh * SEQ * HDIM;
    const u16* klp = kl + bh * SEQ * HDIM;
    const u16* vtp = vT + bh * HDIM * SEQ;

    // Sg fragments: sg*[mt][kc][j], d = kc*32 + quad*8 + j, query = t0+w*32+mt*16+n16
    short8 sgh[2][2], sgl[2][2];
#pragma unroll
    for (int mt = 0; mt < 2; ++mt) {
        int qrow = t0 + w * 32 + mt * 16 + n16;
#pragma unroll
        for (int kc = 0; kc < 2; ++kc) {
            int d0 = kc * 32 + quad * 8;
            float4 q0 = *(const float4*)&qp[(size_t)qrow * HDIM + d0];
            float4 q1 = *(const float4*)&qp[(size_t)qrow * HDIM + d0 + 4];
            float4 k0 = *(const float4*)&ksum[bh * HDIM + d0];
            float4 k1 = *(const float4*)&ksum[bh * HDIM + d0 + 4];
            float4 g0 = *(const float4*)&gdiag[(size_t)h * HDIM + d0];
            float4 g1 = *(const float4*)&gdiag[(size_t)h * HDIM + d0 + 4];
            float sg[8];
            sg[0] = (2048.f * q0.x - k0.x) * g0.x; sg[1] = (2048.f * q0.y - k0.y) * g0.y;
            sg[2] = (2048.f * q0.z - k0.z) * g0.z; sg[3] = (2048.f * q0.w - k0.w) * g0.w;
            sg[4] = (2048.f * q1.x - k1.x) * g1.x; sg[5] = (2048.f * q1.y - k1.y) * g1.y;
            sg[6] = (2048.f * q1.z - k1.z) * g1.z; sg[7] = (2048.f * q1.w - k1.w) * g1.w;
#pragma unroll
            for (int j = 0; j < 8; ++j) {
                u16 hb = f2bf(sg[j]);
                sgh[mt][kc][j] = (short)hb;
                sgl[mt][kc][j] = (short)f2bf(sg[j] - bf2f(hb));
            }
        }
    }

    f32x4 oaccv[2][4] = {};
    f32x4 lgP[2][4];
    float m_n[2] = {-INFINITY, -INFINITY};
    float l_n[2] = {0.f, 0.f};     // lane-local partial sums; reduced in epilogue

    const int srow = tid >> 3;            // 0..31
    const int sc   = tid & 7;             // chunk
    const int scg  = sc * 8;              // global u16 col
    const int scl  = SWZ(srow, sc);       // LDS u16 col

    const int NT = SEQ / 64;              // 32 tiles

    // prologue: stage tile 0 into K-buf 0 / V-buf 0
    *(short8*)&khs[0][srow][scl]      = *(const short8*)&khp[(size_t)srow * HDIM + scg];
    *(short8*)&khs[0][srow + 32][scl] = *(const short8*)&khp[(size_t)(srow + 32) * HDIM + scg];
    *(short8*)&kls[0][srow][scl]      = *(const short8*)&klp[(size_t)srow * HDIM + scg];
    *(short8*)&kls[0][srow + 32][scl] = *(const short8*)&klp[(size_t)(srow + 32) * HDIM + scg];
    *(short8*)&vTs[0][srow][scl]      = *(const short8*)&vtp[(size_t)srow * SEQ + scg];
    *(short8*)&vTs[0][srow + 32][scl] = *(const short8*)&vtp[(size_t)(srow + 32) * SEQ + scg];
    __syncthreads();

    // QK of tile 0 -> lgP, then stage tile 1 into K-buf 1 / V-buf 1 (untouched buffers)
    qk_mfma(lgP, khs[0], kls[0], sgh, sgl, quad, n16);
    {
        const int j0 = 64;
        *(short8*)&khs[1][srow][scl]      = *(const short8*)&khp[(size_t)(j0 + srow) * HDIM + scg];
        *(short8*)&khs[1][srow + 32][scl] = *(const short8*)&khp[(size_t)(j0 + srow + 32) * HDIM + scg];
        *(short8*)&kls[1][srow][scl]      = *(const short8*)&klp[(size_t)(j0 + srow) * HDIM + scg];
        *(short8*)&kls[1][srow + 32][scl] = *(const short8*)&klp[(size_t)(j0 + srow + 32) * HDIM + scg];
        *(short8*)&vTs[1][srow][scl]      = *(const short8*)&vtp[(size_t)srow * SEQ + j0 + scg];
        *(short8*)&vTs[1][srow + 32][scl] = *(const short8*)&vtp[(size_t)(srow + 32) * SEQ + j0 + scg];
    }

    for (int j = 1; j < NT; ++j) {
        __syncthreads();   // tile j staged for all waves; all waves past QK[j-1] & PV[j-2]
        const int kcur = j & 1;
        const int vprev = (j - 1) % 3;
        const bool pf = (j + 1 < NT);

        // T14 issue-early: next tile's global loads
        short8 rk0h, rk1h, rk0l, rk1l, rv0, rv1;
        if (pf) {
            const int jn = (j + 1) * 64;
            rk0h = *(const short8*)&khp[(size_t)(jn + srow) * HDIM + scg];
            rk1h = *(const short8*)&khp[(size_t)(jn + srow + 32) * HDIM + scg];
            rk0l = *(const short8*)&klp[(size_t)(jn + srow) * HDIM + scg];
            rk1l = *(const short8*)&klp[(size_t)(jn + srow + 32) * HDIM + scg];
            rv0  = *(const short8*)&vtp[(size_t)srow * SEQ + jn + scg];
            rv1  = *(const short8*)&vtp[(size_t)(srow + 32) * SEQ + jn + scg];
        }

        // MFMA stream: QK[j] -> lgC ; VALU/DS stream: softmax+PV[j-1] from lgP.
        f32x4 lgC[2][4];
        qk_mfma(lgC, khs[kcur], kls[kcur], sgh, sgl, quad, n16);
        softmax_pv(lgP, m_n, l_n, oaccv, ps[w], vTs[vprev], quad, n16);

        // stage-write tile j+1 (K into buf (j+1)&1; V into buf (j+1)%3)
        if (pf) {
            const int kn = (j + 1) & 1;
            const int vn = (j + 1) % 3;
            *(short8*)&khs[kn][srow][scl] = rk0h;  *(short8*)&khs[kn][srow + 32][scl] = rk1h;
            *(short8*)&kls[kn][srow][scl] = rk0l;  *(short8*)&kls[kn][srow + 32][scl] = rk1l;
            *(short8*)&vTs[vn][srow][scl] = rv0;   *(short8*)&vTs[vn][srow + 32][scl] = rv1;
        }

        // rotate logits
#pragma unroll
        for (int mt = 0; mt < 2; ++mt)
#pragma unroll
            for (int nt = 0; nt < 4; ++nt) lgP[mt][nt] = lgC[mt][nt];
    }

    // drain: softmax+PV of last tile
    softmax_pv(lgP, m_n, l_n, oaccv, ps[w], vTs[(NT - 1) % 3], quad, n16);

    // epilogue: reduce lane-local l, write o_hi bf16, row-major (b, t, h*64+d)
#pragma unroll
    for (int mt = 0; mt < 2; ++mt) {
        float l = l_n[mt];
        l += __shfl_xor(l, 16);
        l += __shfl_xor(l, 32);
        l_n[mt] = l;
    }
#pragma unroll
    for (int mt = 0; mt < 2; ++mt) {
#pragma unroll
        for (int r = 0; r < 4; ++r) {
            float lr = __shfl(l_n[mt], quad * 4 + r);
            float inv = 1.f / lr;
            int t = t0 + w * 32 + mt * 16 + quad * 4 + r;
#pragma unroll
            for (int nt = 0; nt < 4; ++nt) {
                int d = nt * 16 + n16;
                o[((size_t)(b * SEQ + t)) * D_MODEL + h * HDIM + d] = f2bf(oaccv[mt][nt][r] * inv);
            }
        }
    }
}

// ---------------------------------------------------------------- launcher
extern "C" void kernel_launch(void* const* d_in, const int* in_sizes, int n_in,
                              void* d_out, int out_size, void* d_ws, size_t ws_size,
                              hipStream_t stream) {
    const float* x  = (const float*)d_in[0];
    const float* Wq = (const float*)d_in[1];
    const float* bq = (const float*)d_in[2];
    const float* Wk = (const float*)d_in[3];
    const float* bk = (const float*)d_in[4];
    const float* Wv = (const float*)d_in[5];
    const float* bv = (const float*)d_in[6];
    const float* Wo = (const float*)d_in[7];
    const float* bo = (const float*)d_in[8];
    const float* A  = (const float*)d_in[9];
    const float* ll = (const float*)d_in[10];
    float* out = (float*)d_out;

    const size_t NQKV = (size_t)NROWS * D_MODEL;   // 4,194,304
    const size_t NW = (size_t)D_MODEL * D_MODEL;   // 1,048,576
    char* base = (char*)d_ws;
    float* q_ws = (float*)base;            base += NQKV * 4;
    u16* xh  = (u16*)base;                 base += NQKV * 2;   // reused as o_hi after QKV
    u16* xl  = (u16*)base;                 base += NQKV * 2;
    u16* khw = (u16*)base;                 base += NQKV * 2;
    u16* klw = (u16*)base;                 base += NQKV * 2;
    u16* vTw = (u16*)base;                 base += NQKV * 2;   // V^T written directly by merged GEMM
    u16* wqh = (u16*)base;                 base += NW * 2;
    u16* wql = (u16*)base;                 base += NW * 2;
    u16* wkh = (u16*)base;                 base += NW * 2;
    u16* wkl = (u16*)base;                 base += NW * 2;
    u16* wvh = (u16*)base;                 base += NW * 2;
    u16* woh = (u16*)base;                 base += NW * 2;
    float* gd_ws   = (float*)base;         base += NHEAD * HDIM * 4;
    float* ksum_ws = (float*)base;         base += BATCH * NHEAD * HDIM * 4;

    hipMemsetAsync(ksum_ws, 0, BATCH * NHEAD * HDIM * sizeof(float), stream);

    prep_split<<<dim3(4096, 5), 256, 0, stream>>>(x, Wq, Wk, Wv, Wo,
                                                  xh, xl, wqh, wql, wkh, wkl, wvh, woh);
    gdiag_kernel<<<4, 256, 0, stream>>>(A, ll, gd_ws);

    // Fused QKV: z=0 Q (3-pass, split-head fp32), z=1 K (3-pass, k_hi/k_lo + ksum),
    // z=2 V (1-pass, TRANSPOSED bf16 vT). 1536 blocks, bijective XCD decode.
    gemm_mfma<<<1536, 512, 0, stream>>>(
        xh, xl,
        wqh, wql, bq, q_ws, nullptr, nullptr, nullptr,
        wkh, wkl, bk, nullptr, khw, klw, ksum_ws,
        wvh, bv, vTw,
        0b011, (1) | (1 << 4) | (2 << 8));

    u16* ohw = xh;   // alias: x_hi dead after QKV GEMM
    flash_mfma<<<512, 256, 0, stream>>>(
        q_ws, khw, klw, vTw, ksum_ws, gd_ws, ohw);

    // out-proj: 1-pass bf16, row-major fp32 output (grid 512 -> z=0 only)
    gemm_mfma<<<512, 512, 0, stream>>>(
        ohw, nullptr,
        woh, nullptr, bo, out, nullptr, nullptr, nullptr,
        woh, nullptr, bo, out, nullptr, nullptr, nullptr,
        woh, bo, nullptr,
        0, 0);
}